// Round 9
// baseline (346.058 us; speedup 1.0000x reference)
//
#include <hip/hip_runtime.h>
#include <hip/hip_bf16.h>

// Problem constants
constexpr int N_  = 50000;
constexpr int E_  = 800000;
constexpr int ET_ = 850000;   // edges + self loops
constexpr float NEG_SLOPE = 0.2f;

constexpr int SCAN_NB = (N_ + 255) / 256;   // 196 scan blocks

__device__ inline void edge_sd(int e, const int* __restrict__ ei, int& s, int& d) {
    if (e < E_) { s = ei[e]; d = ei[E_ + e]; }
    else        { s = e - E_; d = s; }
}

__device__ inline float leaky(float v) { return fmaxf(v, NEG_SLOPE * v); }

__device__ inline void fma4(float4& a, float s, const float4& w) {
    a.x = fmaf(s, w.x, a.x); a.y = fmaf(s, w.y, a.y);
    a.z = fmaf(s, w.z, a.z); a.w = fmaf(s, w.w, a.w);
}

// bf16 round-to-nearest-even (matches __float2bfloat16)
__device__ inline unsigned bf16rn(float f) {
    union { float f; unsigned u; } v; v.f = f;
    return (v.u + 0x7fffu + ((v.u >> 16) & 1u)) >> 16;
}
__device__ inline unsigned pack2(float lo, float hi) {
    return bf16rn(lo) | (bf16rn(hi) << 16);
}
__device__ inline float2 unpack2(unsigned u) {
    return make_float2(__uint_as_float(u << 16), __uint_as_float(u & 0xffff0000u));
}

// ======================= CSR build (dst-sorted) =======================
__global__ __launch_bounds__(256) void hist_kernel(
        const int* __restrict__ ei, int* __restrict__ count, int* __restrict__ off) {
    int e = blockIdx.x * 256 + threadIdx.x;
    if (e >= ET_) return;
    int s, d; edge_sd(e, ei, s, d);
    off[e] = atomicAdd(&count[d], 1);
}

// ---- 3-kernel parallel exclusive scan of count[N_] -> start[N_] ----
__global__ __launch_bounds__(256) void scan_partial(
        const int* __restrict__ count, int* __restrict__ bsum) {
    __shared__ int red[256];
    int t = threadIdx.x;
    int i = blockIdx.x * 256 + t;
    red[t] = (i < N_) ? count[i] : 0;
    __syncthreads();
    #pragma unroll
    for (int o = 128; o > 0; o >>= 1) {
        if (t < o) red[t] += red[t + o];
        __syncthreads();
    }
    if (t == 0) bsum[blockIdx.x] = red[0];
}

__global__ __launch_bounds__(256) void scan_top(
        const int* __restrict__ bsum, int* __restrict__ bstart) {
    __shared__ int buf[256];
    int t = threadIdx.x;
    int v = (t < SCAN_NB) ? bsum[t] : 0;
    buf[t] = v;
    __syncthreads();
    #pragma unroll
    for (int o = 1; o < 256; o <<= 1) {
        int add = (t >= o) ? buf[t - o] : 0;
        __syncthreads();
        buf[t] += add;
        __syncthreads();
    }
    if (t < SCAN_NB) bstart[t] = buf[t] - v;   // exclusive
}

__global__ __launch_bounds__(256) void scan_final(
        const int* __restrict__ count, const int* __restrict__ bstart,
        int* __restrict__ start) {
    __shared__ int buf[256];
    int t = threadIdx.x;
    int i = blockIdx.x * 256 + t;
    int v = (i < N_) ? count[i] : 0;
    buf[t] = v;
    __syncthreads();
    #pragma unroll
    for (int o = 1; o < 256; o <<= 1) {
        int add = (t >= o) ? buf[t - o] : 0;
        __syncthreads();
        buf[t] += add;
        __syncthreads();
    }
    if (i < N_) start[i] = bstart[blockIdx.x] + buf[t] - v;
}

__global__ __launch_bounds__(256) void scatter_kernel(
        const int* __restrict__ ei, const int* __restrict__ start,
        const int* __restrict__ off, int* __restrict__ csr_src) {
    int e = blockIdx.x * 256 + threadIdx.x;
    if (e >= ET_) return;
    int s, d; edge_sd(e, ei, s, d);
    csr_src[start[d] + off[e]] = s;
}

// ======================= layer 1 node transforms =======================
// 32 rows x 256 out-cols per block; thread: 4 rows x 8 cols of ONE W matrix.
// 32 accs + 8 W float4 resident (launch_bounds(256,2) lifts the VGPR cap —
// r8's 8x8 tile was starved at 68 VGPRs and went latency-bound).
// xl output stored as packed bf16 (value-gather traffic halving in fused1).
__global__ __launch_bounds__(256, 2) void gemm1(
        const float* __restrict__ x,
        const float* __restrict__ Wl, const float* __restrict__ Wr,
        const float* __restrict__ bl, const float* __restrict__ br,
        unsigned* __restrict__ xl1b, float* __restrict__ xr1) {
    __shared__ float xs[32 * 128];          // 16 KB
    const int tid = threadIdx.x;
    const int n0  = blockIdx.x * 32;
    {   // stage 32 rows, coalesced float4 (4 per thread)
        int r   = tid >> 3;                 // 0..31
        int row = n0 + r; if (row >= N_) row = N_ - 1;
        const float4* src = (const float4*)(x + (size_t)row * 128);
        float4* dst = (float4*)(xs + r * 128);
        int c0 = tid & 7;
        #pragma unroll
        for (int i = 0; i < 4; ++i)
            dst[c0 + 8 * i] = src[c0 + 8 * i];
    }
    __syncthreads();
    const int g   = tid >> 5;               // row group 0..7 (4 rows each)
    const int o   = tid & 31;               // col octet
    const bool isR = (o & 16) != 0;         // 0: Wl -> xl1b, 1: Wr -> xr1
    const int col = (o & 15) * 8;
    const float* __restrict__ W = isR ? Wr : Wl;
    const float* __restrict__ rows = xs + g * 4 * 128;
    float4 accA[4], accB[4];
    #pragma unroll
    for (int r = 0; r < 4; ++r) {
        accA[r] = make_float4(0.f, 0.f, 0.f, 0.f);
        accB[r] = make_float4(0.f, 0.f, 0.f, 0.f);
    }
    for (int k = 0; k < 128; k += 4) {
        float4 wA0 = *(const float4*)(W + (size_t)(k+0)*128 + col);
        float4 wB0 = *(const float4*)(W + (size_t)(k+0)*128 + col + 4);
        float4 wA1 = *(const float4*)(W + (size_t)(k+1)*128 + col);
        float4 wB1 = *(const float4*)(W + (size_t)(k+1)*128 + col + 4);
        float4 wA2 = *(const float4*)(W + (size_t)(k+2)*128 + col);
        float4 wB2 = *(const float4*)(W + (size_t)(k+2)*128 + col + 4);
        float4 wA3 = *(const float4*)(W + (size_t)(k+3)*128 + col);
        float4 wB3 = *(const float4*)(W + (size_t)(k+3)*128 + col + 4);
        #pragma unroll
        for (int r = 0; r < 4; ++r) {
            float4 xv = *(const float4*)(rows + r * 128 + k);
            fma4(accA[r], xv.x, wA0); fma4(accB[r], xv.x, wB0);
            fma4(accA[r], xv.y, wA1); fma4(accB[r], xv.y, wB1);
            fma4(accA[r], xv.z, wA2); fma4(accB[r], xv.z, wB2);
            fma4(accA[r], xv.w, wA3); fma4(accB[r], xv.w, wB3);
        }
    }
    const float* __restrict__ bp = isR ? br : bl;
    float4 bA = *(const float4*)(bp + col);
    float4 bB = *(const float4*)(bp + col + 4);
    const int rbase = n0 + g * 4;
    #pragma unroll
    for (int r = 0; r < 4; ++r) {
        int row = rbase + r;
        if (row >= N_) continue;
        float4 vA = accA[r];
        vA.x += bA.x; vA.y += bA.y; vA.z += bA.z; vA.w += bA.w;
        float4 vB = accB[r];
        vB.x += bB.x; vB.y += bB.y; vB.z += bB.z; vB.w += bB.w;
        if (isR) {
            *(float4*)(xr1 + (size_t)row * 128 + col)     = vA;
            *(float4*)(xr1 + (size_t)row * 128 + col + 4) = vB;
        } else {
            uint4 pk;
            pk.x = pack2(vA.x, vA.y);
            pk.y = pack2(vA.z, vA.w);
            pk.z = pack2(vB.x, vB.y);
            pk.w = pack2(vB.z, vB.w);
            *(uint4*)(xl1b + (size_t)row * 64 + col / 2) = pk;
        }
    }
}

// ====== layer 1 fused attention: ONE wave per node, bf16-pair gathers ======
__global__ __launch_bounds__(256) void fused1(
        const int* __restrict__ csr_src, const int* __restrict__ start,
        const int* __restrict__ count,
        const unsigned* __restrict__ xl1b, const float* __restrict__ xr1,
        const float* __restrict__ att, const float* __restrict__ bias1,
        float* __restrict__ hout) {
    int t = blockIdx.x * 256 + threadIdx.x;
    int n = __builtin_amdgcn_readfirstlane(t >> 6);   // wave-uniform node id
    int lane = t & 63;
    if (n >= N_) return;
    float2 xr = *(const float2*)(xr1 + (size_t)n * 128 + 2 * lane);
    float2 av = *(const float2*)(att + 2 * lane);
    int p0 = __builtin_amdgcn_readfirstlane(start[n]);
    int p1 = p0 + __builtin_amdgcn_readfirstlane(count[n]);
    float2 acc = make_float2(0.f, 0.f);
    float l = 0.f;
    for (int p = p0; p < p1; p += 4) {
        int q1 = p + 1 < p1 ? p + 1 : p1 - 1;
        int q2 = p + 2 < p1 ? p + 2 : p1 - 1;
        int q3 = p + 3 < p1 ? p + 3 : p1 - 1;
        int s0 = __builtin_amdgcn_readfirstlane(csr_src[p]);
        int s1 = __builtin_amdgcn_readfirstlane(csr_src[q1]);
        int s2 = __builtin_amdgcn_readfirstlane(csr_src[q2]);
        int s3 = __builtin_amdgcn_readfirstlane(csr_src[q3]);
        float2 x0 = unpack2(xl1b[(size_t)s0 * 64 + lane]);
        float2 x1 = unpack2(xl1b[(size_t)s1 * 64 + lane]);
        float2 x2 = unpack2(xl1b[(size_t)s2 * 64 + lane]);
        float2 x3 = unpack2(xl1b[(size_t)s3 * 64 + lane]);
        float a0 = fmaf(leaky(x0.x + xr.x), av.x, leaky(x0.y + xr.y) * av.y);
        float a1 = fmaf(leaky(x1.x + xr.x), av.x, leaky(x1.y + xr.y) * av.y);
        float a2 = fmaf(leaky(x2.x + xr.x), av.x, leaky(x2.y + xr.y) * av.y);
        float a3 = fmaf(leaky(x3.x + xr.x), av.x, leaky(x3.y + xr.y) * av.y);
        a0 += __shfl_xor(a0, 1); a1 += __shfl_xor(a1, 1);
        a2 += __shfl_xor(a2, 1); a3 += __shfl_xor(a3, 1);
        a0 += __shfl_xor(a0, 2); a1 += __shfl_xor(a1, 2);
        a2 += __shfl_xor(a2, 2); a3 += __shfl_xor(a3, 2);
        a0 += __shfl_xor(a0, 4); a1 += __shfl_xor(a1, 4);
        a2 += __shfl_xor(a2, 4); a3 += __shfl_xor(a3, 4);
        float w0 = __expf(a0);
        float w1 = p + 1 < p1 ? __expf(a1) : 0.f;
        float w2 = p + 2 < p1 ? __expf(a2) : 0.f;
        float w3 = p + 3 < p1 ? __expf(a3) : 0.f;
        acc.x = fmaf(w0, x0.x, acc.x); acc.y = fmaf(w0, x0.y, acc.y); l += w0;
        acc.x = fmaf(w1, x1.x, acc.x); acc.y = fmaf(w1, x1.y, acc.y); l += w1;
        acc.x = fmaf(w2, x2.x, acc.x); acc.y = fmaf(w2, x2.y, acc.y); l += w2;
        acc.x = fmaf(w3, x3.x, acc.x); acc.y = fmaf(w3, x3.y, acc.y); l += w3;
    }
    float2 bv = *(const float2*)(bias1 + 2 * lane);
    float vx = acc.x / l + bv.x;
    float vy = acc.y / l + bv.y;
    float2 o;
    o.x = vx > 0.f ? vx : (__expf(vx) - 1.f);
    o.y = vy > 0.f ? vy : (__expf(vy) - 1.f);
    *(float2*)(hout + (size_t)n * 128 + 2 * lane) = o;
}

// ======================= layer 2 node transforms =======================
// 64 rows x 128 out-cols per block; thread: 4 rows x 8 cols of ONE W matrix.
__global__ __launch_bounds__(256, 2) void gemm2(
        const float* __restrict__ hbuf,
        const float* __restrict__ Wl, const float* __restrict__ Wr,
        const float* __restrict__ bl, const float* __restrict__ br,
        unsigned* __restrict__ xl2b, float* __restrict__ xr2) {
    __shared__ float hs[64 * 128];          // 32 KB
    const int tid = threadIdx.x;
    const int n0  = blockIdx.x * 64;
    {   // stage 64 rows, coalesced float4 (8 per thread)
        int r   = tid >> 2;                 // 0..63
        int row = n0 + r; if (row >= N_) row = N_ - 1;
        const float4* src = (const float4*)(hbuf + (size_t)row * 128);
        float4* dst = (float4*)(hs + r * 128);
        int c0 = tid & 3;
        #pragma unroll
        for (int i = 0; i < 8; ++i)
            dst[c0 + 4 * i] = src[c0 + 4 * i];
    }
    __syncthreads();
    const int g   = tid >> 4;               // row group 0..15 (4 rows each)
    const int o   = tid & 15;               // col octet
    const bool isR = (o & 8) != 0;          // 0: Wl -> xl2b, 1: Wr -> xr2
    const int col = (o & 7) * 8;
    const float* __restrict__ W = isR ? Wr : Wl;
    const float* __restrict__ rows = hs + g * 4 * 128;
    float4 accA[4], accB[4];
    #pragma unroll
    for (int r = 0; r < 4; ++r) {
        accA[r] = make_float4(0.f, 0.f, 0.f, 0.f);
        accB[r] = make_float4(0.f, 0.f, 0.f, 0.f);
    }
    for (int k = 0; k < 128; k += 4) {
        float4 wA0 = *(const float4*)(W + (size_t)(k+0)*64 + col);
        float4 wB0 = *(const float4*)(W + (size_t)(k+0)*64 + col + 4);
        float4 wA1 = *(const float4*)(W + (size_t)(k+1)*64 + col);
        float4 wB1 = *(const float4*)(W + (size_t)(k+1)*64 + col + 4);
        float4 wA2 = *(const float4*)(W + (size_t)(k+2)*64 + col);
        float4 wB2 = *(const float4*)(W + (size_t)(k+2)*64 + col + 4);
        float4 wA3 = *(const float4*)(W + (size_t)(k+3)*64 + col);
        float4 wB3 = *(const float4*)(W + (size_t)(k+3)*64 + col + 4);
        #pragma unroll
        for (int r = 0; r < 4; ++r) {
            float4 xv = *(const float4*)(rows + r * 128 + k);
            fma4(accA[r], xv.x, wA0); fma4(accB[r], xv.x, wB0);
            fma4(accA[r], xv.y, wA1); fma4(accB[r], xv.y, wB1);
            fma4(accA[r], xv.z, wA2); fma4(accB[r], xv.z, wB2);
            fma4(accA[r], xv.w, wA3); fma4(accB[r], xv.w, wB3);
        }
    }
    const float* __restrict__ bp = isR ? br : bl;
    float4 bA = *(const float4*)(bp + col);
    float4 bB = *(const float4*)(bp + col + 4);
    const int rbase = n0 + g * 4;
    #pragma unroll
    for (int r = 0; r < 4; ++r) {
        int row = rbase + r;
        if (row >= N_) continue;
        float4 vA = accA[r];
        vA.x += bA.x; vA.y += bA.y; vA.z += bA.z; vA.w += bA.w;
        float4 vB = accB[r];
        vB.x += bB.x; vB.y += bB.y; vB.z += bB.z; vB.w += bB.w;
        if (isR) {
            *(float4*)(xr2 + (size_t)row * 64 + col)     = vA;
            *(float4*)(xr2 + (size_t)row * 64 + col + 4) = vB;
        } else {
            uint4 pk;
            pk.x = pack2(vA.x, vA.y);
            pk.y = pack2(vA.z, vA.w);
            pk.z = pack2(vB.x, vB.y);
            pk.w = pack2(vB.z, vB.w);
            *(uint4*)(xl2b + (size_t)row * 32 + col / 2) = pk;
        }
    }
}

// ====== layer 2 fused attention: one wave per node, TWO edges at a time ======
__global__ __launch_bounds__(256) void fused2(
        const int* __restrict__ csr_src, const int* __restrict__ start,
        const int* __restrict__ count,
        const unsigned* __restrict__ xl2b, const float* __restrict__ xr2,
        const float* __restrict__ att, const float* __restrict__ bias2,
        float* __restrict__ out) {
    int t = blockIdx.x * 256 + threadIdx.x;
    int n = __builtin_amdgcn_readfirstlane(t >> 6);   // wave-uniform node id
    int lane = t & 63;
    int half = lane >> 5;                 // which edge of the pair
    int lc   = lane & 31;                 // channel pair id
    if (n >= N_) return;
    float2 xr = *(const float2*)(xr2 + (size_t)n * 64 + 2 * lc);
    float2 av = *(const float2*)(att + 2 * lc);
    int p0 = __builtin_amdgcn_readfirstlane(start[n]);
    int p1 = p0 + __builtin_amdgcn_readfirstlane(count[n]);
    float2 acc = make_float2(0.f, 0.f);
    float l = 0.f;
    for (int p = p0; p < p1; p += 8) {
        #pragma unroll
        for (int u = 0; u < 4; ++u) {
            int pe = p + 2 * u + half;
            int pc = pe < p1 ? pe : p1 - 1;
            int s  = csr_src[pc];
            float2 xv = unpack2(xl2b[(size_t)s * 32 + lc]);
            float a = fmaf(leaky(xv.x + xr.x), av.x, leaky(xv.y + xr.y) * av.y);
            a += __shfl_xor(a, 1);
            a += __shfl_xor(a, 2);
            a += __shfl_xor(a, 4);
            a += __shfl_xor(a, 8);
            a += __shfl_xor(a, 16);
            float w = pe < p1 ? __expf(a) : 0.f;
            acc.x = fmaf(w, xv.x, acc.x);
            acc.y = fmaf(w, xv.y, acc.y);
            l += w;
        }
    }
    acc.x += __shfl_xor(acc.x, 32);
    acc.y += __shfl_xor(acc.y, 32);
    l     += __shfl_xor(l, 32);
    if (half == 0) {
        float2 bv = *(const float2*)(bias2 + 2 * lc);
        float2 o;
        o.x = acc.x / l + bv.x;
        o.y = acc.y / l + bv.y;
        *(float2*)(out + (size_t)n * 64 + 2 * lc) = o;
    }
}

extern "C" void kernel_launch(void* const* d_in, const int* in_sizes, int n_in,
                              void* d_out, int out_size, void* d_ws, size_t ws_size,
                              hipStream_t stream) {
    (void)in_sizes; (void)n_in; (void)out_size; (void)ws_size;
    const float* x     = (const float*)d_in[0];
    const int*   ei    = (const int*)d_in[1];
    const float* W1l   = (const float*)d_in[2];
    const float* b1l   = (const float*)d_in[3];
    const float* W1r   = (const float*)d_in[4];
    const float* b1r   = (const float*)d_in[5];
    const float* att1  = (const float*)d_in[6];
    const float* bias1 = (const float*)d_in[7];
    const float* W2l   = (const float*)d_in[8];
    const float* b2l   = (const float*)d_in[9];
    const float* W2r   = (const float*)d_in[10];
    const float* b2r   = (const float*)d_in[11];
    const float* att2  = (const float*)d_in[12];
    const float* bias2 = (const float*)d_in[13];
    float* out = (float*)d_out;

    // workspace layout
    float* xr1      = (float*)d_ws;              // 6,400,000 f
    float* hbuf     = xr1 + 6400000;             // 6,400,000 f
    unsigned* xl1b  = (unsigned*)(hbuf + 6400000); // 3,200,000 u (bf16 pairs)
    int* count   = (int*)(xl1b + 3200000);       //    50,000 i
    int* startp  = count + 50000;                //    50,000 i
    int* off     = startp + 50000;               //   850,000 i
    int* csr_src = off + 850000;                 //   850,000 i
    int* bsum    = csr_src + 850000;             //       256 i
    int* bstart  = bsum + 256;                   //       256 i
    unsigned* xl2b = xl1b;                       // alias: xl1b dead after fused1
    float* xr2     = xr1;                        // alias: xr1 dead after fused1

    hipMemsetAsync((void*)count, 0, 50000 * sizeof(int), stream);

    const int EB = (ET_ + 255) / 256;
    hist_kernel <<<EB, 256, 0, stream>>>(ei, count, off);
    scan_partial<<<SCAN_NB, 256, 0, stream>>>(count, bsum);
    scan_top    <<<1, 256, 0, stream>>>(bsum, bstart);
    scan_final  <<<SCAN_NB, 256, 0, stream>>>(count, bstart, startp);
    scatter_kernel<<<EB, 256, 0, stream>>>(ei, startp, off, csr_src);

    gemm1 <<<(N_ + 31) / 32, 256, 0, stream>>>(x, W1l, W1r, b1l, b1r, xl1b, xr1);
    fused1<<<(N_ * 64 + 255) / 256, 256, 0, stream>>>(csr_src, startp, count,
                                                      xl1b, xr1, att1, bias1, hbuf);

    gemm2 <<<(N_ + 63) / 64, 256, 0, stream>>>(hbuf, W2l, W2r, b2l, b2r, xl2b, xr2);
    fused2<<<(N_ * 64 + 255) / 256, 256, 0, stream>>>(csr_src, startp, count,
                                                      xl2b, xr2, att2, bias2, out);
}